// Round 1
// baseline (247.186 us; speedup 1.0000x reference)
//
#include <hip/hip_runtime.h>

// GCN_77584289234976 — round 8.
// R7 counters: k_mega2 = 77us, 227MB @ 2.9TB/s, MfmaUtil 22% -> dominated by
// streaming W_t (134MB write) which k_apply re-reads (134MB). W is a pure
// intermediate worth only 12.9 GFLOP. R8: fuse gen+apply (k_genapply): W
// generated in 32-ki LDS tiles (40.5KB) and consumed in-place per node;
// out accumulated in registers. W_t eliminated (-270MB HBM round-trip).
// k_mega2 -> aggr-only; k_apply deleted. Re-reads shift to L2/L3: pool 268MB,
// xg 268MB; bid = og*64+ng keeps o-siblings of a node group on one XCD so the
// 512KB xg slice is L2-resident.
// MFMA 16x16x32 bf16 layout contract (m89/m97/m120):
//   a-frag: A[m][k], m=lane&15, k=(lane>>4)*8+j
//   b-frag: B[k][n], n=lane&15, k=(lane>>4)*8+j
//   d:      D[m][n], n(col)=lane&15, m(row)=(lane>>4)*4+reg

typedef unsigned short u16;
typedef unsigned int u32;
typedef __attribute__((ext_vector_type(8))) short bf16x8;
typedef __attribute__((ext_vector_type(4))) float f32x4;
typedef const __attribute__((address_space(1))) u16* gas1;
typedef __attribute__((address_space(3))) u16* las3;

#define NN 2048
#define EE 64
#define CC 128
#define BB 32

__device__ __forceinline__ u16 f2bf(float f) {
  u32 u = __builtin_bit_cast(u32, f);
  u += 0x7fffu + ((u >> 16) & 1u);   // round-to-nearest-even
  return (u16)(u >> 16);
}

__device__ __forceinline__ f32x4 mfma16(bf16x8 a, bf16x8 b, f32x4 c) {
  return __builtin_amdgcn_mfma_f32_16x16x32_bf16(a, b, c, 0, 0, 0);
}

// ---------------- mega0: prep(512) + poolt(256) + xtrans(1024), block-ranged
__global__ __launch_bounds__(256) void k_mega0(
    const float* __restrict__ x, const float* __restrict__ ne,
    const float* __restrict__ te, const float* __restrict__ pool,
    const float* __restrict__ bias_pool, const float* __restrict__ lnw,
    const float* __restrict__ lnb,
    float* __restrict__ e, u16* __restrict__ e_bf, float* __restrict__ bias_out,
    u16* __restrict__ pool_r, u16* __restrict__ x_t, u16* __restrict__ xg_t) {
  __shared__ __align__(16) char smem[33280];
  int bid = blockIdx.x;
  int tid = threadIdx.x;
  if (bid < 512) {
    // ---- prep: 4 nodes/block, one wave per node
    float* sh = (float*)smem;             // [4][64]
    int nw = tid >> 6, d = tid & 63;
    int n = bid * 4 + nw;
    float v = ne[n * EE + d] + te[d];
    float s = v;
#pragma unroll
    for (int off = 32; off > 0; off >>= 1) s += __shfl_xor(s, off);
    float mean = s * (1.0f / 64.0f);
    float c = v - mean;
    float q = c * c;
#pragma unroll
    for (int off = 32; off > 0; off >>= 1) q += __shfl_xor(q, off);
    float inv = rsqrtf(q * (1.0f / 64.0f) + 1e-12f);
    float ev = c * inv * lnw[d] + lnb[d];
    e[n * EE + d] = ev;
    e_bf[n * EE + d] = f2bf(ev);
    sh[nw * 64 + d] = ev;
    __syncthreads();
#pragma unroll
    for (int oo = 0; oo < 2; ++oo) {
      int o = oo * 64 + d;
      float acc = 0.f;
#pragma unroll 8
      for (int dd = 0; dd < 64; ++dd) acc += sh[nw * 64 + dd] * bias_pool[dd * CC + o];
      bias_out[n * CC + o] = acc;
    }
  } else if (bid < 768) {
    // ---- poolt: pool [d][ki][o] fp32 -> pool_r [(o,ki)][d] bf16
    float* t = (float*)smem;              // [128][65]
    int ki = bid - 512;
    for (int it = 0; it < 32; ++it) {
      int idx = it * 256 + tid;
      int d = idx >> 7, o = idx & 127;
      t[o * 65 + d] = pool[d * 32768 + ki * 128 + o];
    }
    __syncthreads();
    for (int it = 0; it < 32; ++it) {
      int idx = it * 256 + tid;
      int o = idx >> 6, d = idx & 63;
      pool_r[((size_t)o * 256 + ki) * 64 + d] = f2bf(t[o * 65 + d]);
    }
  } else {
    // ---- xtrans: x -> x_t [b][c][m] bf16 and xg_t [m][b][0..128) bf16
    u16* t = (u16*)smem;                  // [128][68]
    int bx = bid - 768;
    int b = bx >> 5;
    int m0 = (bx & 31) * 64;
    for (int it = 0; it < 32; ++it) {
      int idx = it * 256 + tid;
      int m = idx >> 7, c = idx & 127;
      float v = x[((size_t)b * NN + m0 + m) * CC + c];
      t[c * 68 + m] = f2bf(v);
    }
    __syncthreads();
    for (int it = 0; it < 32; ++it) {
      int idx = it * 256 + tid;
      int c = idx >> 6, m = idx & 63;
      x_t[((size_t)b * CC + c) * NN + m0 + m] = t[c * 68 + m];
    }
    for (int it = 0; it < 16; ++it) {
      int idx = it * 256 + tid;
      int m = idx >> 6, c2 = idx & 63;
      float2 v = *(const float2*)&x[((size_t)b * NN + m0 + m) * CC + c2 * 2];
      u32 pk = (u32)f2bf(v.x) | ((u32)f2bf(v.y) << 16);
      *(u32*)&xg_t[(((size_t)(m0 + m)) * 32 + b) * 256 + c2 * 2] = pk;
    }
  }
}

// ---------------- k_Sexp: P = exp(e @ e^T) bf16 + atomic row sums.
// 64x64 tile (35KB LDS -> 4 blk/CU), 4x4 per thread, no max-sub (|S|<=64).
__global__ __launch_bounds__(256) void k_Sexp(const float* __restrict__ e,
                                              u16* __restrict__ P,
                                              float* __restrict__ rs) {
  __shared__ float er[64 * 68];
  __shared__ float ec[64 * 68];
  int n0 = (blockIdx.x >> 5) * 64, m0 = (blockIdx.x & 31) * 64;
  int tid = threadIdx.x;
  for (int it = 0; it < 16; ++it) {
    int idx = it * 256 + tid;
    int r = idx >> 6, d = idx & 63;
    er[r * 68 + d] = e[(n0 + r) * EE + d];
    ec[r * 68 + d] = e[(m0 + r) * EE + d];
  }
  __syncthreads();
  int tx = tid & 15, ty = tid >> 4;
  float acc[4][4] = {};
  for (int d4 = 0; d4 < 64; d4 += 4) {
    f32x4 av[4], bv[4];
#pragma unroll
    for (int i = 0; i < 4; ++i) av[i] = *(const f32x4*)&er[(ty + 16 * i) * 68 + d4];
#pragma unroll
    for (int j = 0; j < 4; ++j) bv[j] = *(const f32x4*)&ec[(tx + 16 * j) * 68 + d4];
#pragma unroll
    for (int i = 0; i < 4; ++i)
#pragma unroll
      for (int j = 0; j < 4; ++j) {
        acc[i][j] += av[i][0] * bv[j][0];
        acc[i][j] += av[i][1] * bv[j][1];
        acc[i][j] += av[i][2] * bv[j][2];
        acc[i][j] += av[i][3] * bv[j][3];
      }
  }
#pragma unroll
  for (int i = 0; i < 4; ++i) {
    float s = 0.f;
#pragma unroll
    for (int j = 0; j < 4; ++j) {
      float pv = __expf(acc[i][j]);
      P[(size_t)(n0 + ty + 16 * i) * NN + m0 + tx + 16 * j] = f2bf(pv);
      s += pv;
    }
#pragma unroll
    for (int off = 8; off > 0; off >>= 1) s += __shfl_xor(s, off);  // reduce over tx
    if (tx == 0) atomicAdd(&rs[n0 + ty + 16 * i], s);
  }
}

// ---------------- k_aggr: x_agg[b] = (P @ x[b]) / l  (m97 staging) -> xg_t upper half.
__global__ __launch_bounds__(256, 4) void k_aggr(
    const u16* __restrict__ P, const u16* __restrict__ x_t,
    const float* __restrict__ rs, u16* __restrict__ xg_t) {
  __shared__ __align__(16) char smem[32768];
  int tid = threadIdx.x;
  int lane = tid & 63, w = tid >> 6;
  int lm = lane & 15, lq = lane >> 4;
  u16* As = (u16*)smem;               // [128][64] unpadded (global_load_lds)
  u16* Bs = (u16*)(smem + 16384);
  int mb = blockIdx.x & 15, b = blockIdx.x >> 4;
  int n0 = mb * 128;
  int wm = w >> 1, wn = w & 1;
  f32x4 acc[4][4] = {};
  const u16* a_src = P + (size_t)n0 * NN;
  const u16* b_src = x_t + (size_t)b * CC * NN;
  for (int kc = 0; kc < NN; kc += 64) {
    __syncthreads();
#pragma unroll
    for (int ii = 0; ii < 4; ++ii) {
      int idx = ii * 256 + tid;
      int row = idx >> 3, ch = idx & 7;
      __builtin_amdgcn_global_load_lds((gas1)(a_src + (size_t)row * NN + kc + ch * 8),
                                       (las3)(As + (size_t)(ii * 256 + w * 64) * 8), 16, 0, 0);
      __builtin_amdgcn_global_load_lds((gas1)(b_src + (size_t)row * NN + kc + ch * 8),
                                       (las3)(Bs + (size_t)(ii * 256 + w * 64) * 8), 16, 0, 0);
    }
    __syncthreads();
#pragma unroll
    for (int kk = 0; kk < 64; kk += 32) {
      bf16x8 af[4], bq[4];
#pragma unroll
      for (int i = 0; i < 4; ++i)
        af[i] = *(const bf16x8*)&As[(wm * 64 + i * 16 + lm) * 64 + kk + lq * 8];
#pragma unroll
      for (int j = 0; j < 4; ++j)
        bq[j] = *(const bf16x8*)&Bs[(wn * 64 + j * 16 + lm) * 64 + kk + lq * 8];
#pragma unroll
      for (int i = 0; i < 4; ++i)
#pragma unroll
        for (int j = 0; j < 4; ++j)
          acc[i][j] = mfma16(af[i], bq[j], acc[i][j]);
    }
  }
#pragma unroll
  for (int i = 0; i < 4; ++i) {
    int nr = n0 + wm * 64 + i * 16 + lq * 4;
#pragma unroll
    for (int r = 0; r < 4; ++r) {
      float sc = 1.0f / rs[nr + r];
#pragma unroll
      for (int j = 0; j < 4; ++j) {
        int c = wn * 64 + j * 16 + lm;
        xg_t[((size_t)(nr + r) * 32 + b) * 256 + 128 + c] = f2bf(acc[i][j][r] * sc);
      }
    }
  }
}

// ---------------- k_genapply: fused W-gen + apply. Never materializes W.
// Grid 512 = 8 og x 64 ng (bid = og*64 + ng -> o-siblings of a node group share
// an XCD: 512KB xg slice L2-resident, 8x reuse; pool slices spread per XCD).
// Block: 32 nodes x 16 o-cols, all 32 batches. Per 32-ki tile:
//   gen: D[col(ki)][node] = pool_r[col][d] x e_bf[node][d] -> bf16 -> LDS
//   apply: D[o][b] = W_lds[n][o][ki] x xg[b][n][ki], acc in regs (64 f32/thr)
// LDS W: [32 nodes][16 o][32 ki], o-stride 40 elems (16B-aligned b128 reads,
// 8-way spread), node-stride 648 (=16*40+8, rotates banks by 4/node). 40.5KB.
#define GA_OS 40
#define GA_NS 648
__global__ __launch_bounds__(256) void k_genapply(
    const u16* __restrict__ e_bf, const u16* __restrict__ pool_r,
    const u16* __restrict__ xg_t, const float* __restrict__ biasb,
    float* __restrict__ out) {
  __shared__ u16 W[32 * GA_NS];   // 41472 B
  int tid = threadIdx.x;
  int lane = tid & 63, w = tid >> 6;
  int lm = lane & 15, lq = lane >> 4;
  int ng = blockIdx.x & 63, og = blockIdx.x >> 6;
  int n0 = ng * 32, o0 = og * 16;

  // e b-frags: B[k=d][n=node], node = n0 + nc*16 + lm, d = ks*32 + lq*8 + j
  bf16x8 eB[2][2];
#pragma unroll
  for (int nc = 0; nc < 2; ++nc)
#pragma unroll
    for (int ks = 0; ks < 2; ++ks)
      eB[nc][ks] = *(const bf16x8*)&e_bf[(n0 + nc * 16 + lm) * EE + ks * 32 + lq * 8];

  f32x4 acc[8][2] = {};
  for (int kt = 0; kt < 8; ++kt) {
    int ki0 = kt * 32;
    if (kt) __syncthreads();   // prev apply reads done before W overwrite
    // ---- gen: wave w covers o_l = w*4..w*4+3, all 32 nodes, 32 ki
#pragma unroll
    for (int ot = 0; ot < 4; ++ot) {
      int o_l = w * 4 + ot;
      const u16* pb = pool_r + ((size_t)(o0 + o_l) * 256 + ki0 + lm) * 64 + lq * 8;
#pragma unroll
      for (int kc = 0; kc < 2; ++kc) {
        const u16* ap = pb + kc * 16 * 64;
        bf16x8 a0 = *(const bf16x8*)ap;          // d = lq*8..
        bf16x8 a1 = *(const bf16x8*)(ap + 32);   // d = 32+lq*8..
#pragma unroll
        for (int nc = 0; nc < 2; ++nc) {
          f32x4 d = {0.f, 0.f, 0.f, 0.f};
          d = mfma16(a0, eB[nc][0], d);
          d = mfma16(a1, eB[nc][1], d);
          // D: node = lm (col), ki_local = kc*16 + lq*4 + r (row)
          ushort4 h;
          h.x = f2bf(d[0]); h.y = f2bf(d[1]); h.z = f2bf(d[2]); h.w = f2bf(d[3]);
          *(ushort4*)&W[(nc * 16 + lm) * GA_NS + o_l * GA_OS + kc * 16 + lq * 4] = h;
        }
      }
    }
    __syncthreads();
    // ---- apply: wave w covers nodes w*8..w*8+7
#pragma unroll
    for (int i = 0; i < 8; ++i) {
      int n_l = w * 8 + i;
      // a-frag: A[m=o][k=ki] = W[n][o=lm][ki=lq*8+j]
      bf16x8 wA = *(const bf16x8*)&W[n_l * GA_NS + lm * GA_OS + lq * 8];
      // b-frags: B[k=ki][n=b] = xg_t[n][b=lm(+16)][ki0+lq*8+j]
      const u16* xp = xg_t + ((size_t)(n0 + n_l) * 32) * 256 + ki0 + lq * 8;
      bf16x8 x0 = *(const bf16x8*)(xp + lm * 256);
      bf16x8 x1 = *(const bf16x8*)(xp + (16 + lm) * 256);
      acc[i][0] = mfma16(wA, x0, acc[i][0]);
      acc[i][1] = mfma16(wA, x1, acc[i][1]);
    }
  }
  // ---- epilogue: D[m=o][n=b]: b = bt*16+lm, o = o0 + lq*4 + r
#pragma unroll
  for (int i = 0; i < 8; ++i) {
    int n = n0 + w * 8 + i;
    float4 bv = *(const float4*)&biasb[n * CC + o0 + lq * 4];
#pragma unroll
    for (int bt = 0; bt < 2; ++bt) {
      int b = bt * 16 + lm;
      float4 o4;
      o4.x = acc[i][bt][0] + bv.x;
      o4.y = acc[i][bt][1] + bv.y;
      o4.z = acc[i][bt][2] + bv.z;
      o4.w = acc[i][bt][3] + bv.w;
      *(float4*)&out[((size_t)b * NN + n) * CC + o0 + lq * 4] = o4;
    }
  }
}

extern "C" void kernel_launch(void* const* d_in, const int* in_sizes, int n_in,
                              void* d_out, int out_size, void* d_ws, size_t ws_size,
                              hipStream_t stream) {
  const float* x        = (const float*)d_in[0];
  const float* node_emb = (const float*)d_in[1];
  const float* time_emb = (const float*)d_in[2];
  const float* pool     = (const float*)d_in[3];
  const float* bias_pl  = (const float*)d_in[4];
  const float* ln_w     = (const float*)d_in[5];
  const float* ln_b     = (const float*)d_in[6];
  float* out = (float*)d_out;

  char* p = (char*)d_ws;
  auto alloc = [&](size_t bytes) {
    char* r = p;
    p += (bytes + 255) & ~(size_t)255;
    return r;
  };
  float* e      = (float*)alloc((size_t)NN * EE * 4);
  u16*   e_bf   = (u16*)  alloc((size_t)NN * EE * 2);
  float* biasb  = (float*)alloc((size_t)NN * CC * 4);
  u16*   Pm     = (u16*)  alloc((size_t)NN * NN * 2);          // exp(S), unnormalized
  float* rs     = (float*)alloc((size_t)NN * 4);               // row sums
  u16*   x_t    = (u16*)  alloc((size_t)BB * CC * NN * 2);
  u16*   xg_t   = (u16*)  alloc((size_t)NN * BB * 256 * 2);    // [node][batch][x||xagg]
  u16*   pool_r = (u16*)  alloc((size_t)128 * 256 * 64 * 2);

  if (ws_size < (size_t)(p - (char*)d_ws)) return;

  (void)hipMemsetAsync(rs, 0, (size_t)NN * 4, stream);

  k_mega0<<<1792, 256, 0, stream>>>(x, node_emb, time_emb, pool, bias_pl, ln_w, ln_b,
                                    e, e_bf, biasb, pool_r, x_t, xg_t);
  k_Sexp<<<1024, 256, 0, stream>>>(e, Pm, rs);
  k_aggr<<<512, 256, 0, stream>>>(Pm, x_t, rs, xg_t);
  k_genapply<<<512, 256, 0, stream>>>(e_bf, pool_r, xg_t, biasb, out);
}